// Round 6
// baseline (769.700 us; speedup 1.0000x reference)
//
#include <hip/hip_runtime.h>

// ---------------------------------------------------------------------------
// 2-layer GCN + global mean pool, MI355X (gfx950).  ALL-FP32.
//   A_hat = D^{-1/2}(A+I)D^{-1/2}
//   H   = relu( (A_hat X) @ W1 + b1 )        [aggregate-first, GEMM in-place]
//   out = pool( A_hat H ) @ W2 + b2          [pool-first: no relu on layer 2]
// R6: (1) agg2+pool in PUSH form: CSC by src, stream h once, LDS 64x128 pool
//     accumulator (was 328 MB random gather -> ~31 MB stream);
//     (2) agg1: half-wave/node (float4) + unroll2 = 4x request streams;
//     (3) CSR+CSC built in one fused count/scan/fill pipeline.
// ---------------------------------------------------------------------------

#define D 128
#define NGRAPH 64
#define AGG_BLOCKS 2048    // agg1: 16384 half-wave streams
#define PUSH_BLOCKS 512    // agg2 push: 2048 waves, 32KB LDS pool each
#define SCAN_B 1024

// --- diagnostic: all-zero output (ws too small) ----------------------------
__global__ void zero_out_kernel(float* __restrict__ out, int n) {
    int i = blockIdx.x * blockDim.x + threadIdx.x;
    if (i < n) out[i] = 0.f;
}

// --- CSR(by dst) + CSC(by src) build ---------------------------------------
// deg: [0,N)=dst-degree, [N,2N)=src-degree
__global__ void count_kernel(const int* __restrict__ ei, int* __restrict__ deg,
                             int E, int N) {
    int e = blockIdx.x * blockDim.x + threadIdx.x;
    if (e < E) {
        int d = ei[E + e];
        int s = ei[e];
        if (d >= 0 && d < N) atomicAdd(&deg[d], 1);
        if (s >= 0 && s < N) atomicAdd(&deg[N + s], 1);
    }
}

// K1: per-block scan over two concatenated segments (dst | src).
// nblk blocks per segment; rowstart_all = [rowstart_dst(N+1) | rowstart_src(N+1)]
__global__ __launch_bounds__(SCAN_B) void block_scan_kernel(const int* __restrict__ deg,
                                                            int* __restrict__ rowstart_all,
                                                            int* __restrict__ bsum,
                                                            int N, int nblk) {
    __shared__ int sc[SCAN_B];
    int t = threadIdx.x;
    int seg = (blockIdx.x >= nblk) ? 1 : 0;
    int lb  = blockIdx.x - seg * nblk;
    int i   = lb * SCAN_B + t;
    int v = (i < N) ? deg[seg * N + i] : 0;
    int orig = v;
    sc[t] = v;
    __syncthreads();
    for (int off = 1; off < SCAN_B; off <<= 1) {
        int add = (t >= off) ? sc[t - off] : 0;
        __syncthreads();
        v += add;
        sc[t] = v;
        __syncthreads();
    }
    if (i < N) rowstart_all[seg * (N + 1) + i] = v - orig;  // local exclusive
    if (t == SCAN_B - 1) bsum[blockIdx.x] = v;
}

// K2: two waves; wave w scans segment w's block sums (nblk<=64).
__global__ __launch_bounds__(128) void scan_sums_kernel(int* __restrict__ bsum, int nblk) {
    int wave = threadIdx.x >> 6, lane = threadIdx.x & 63;
    int idx = wave * nblk + lane;
    int v = (lane < nblk) ? bsum[idx] : 0;
    int orig = v;
    for (int off = 1; off < 64; off <<= 1) {
        int u = __shfl_up(v, off);
        if (lane >= off) v += u;
    }
    if (lane < nblk) bsum[idx] = v - orig;   // exclusive block offset
}

// K3: add block offsets; init cursors; dinv from dst-degree; totals.
__global__ __launch_bounds__(SCAN_B) void finalize_scan_kernel(const int* __restrict__ deg,
                                                               const int* __restrict__ bsum,
                                                               int* __restrict__ rowstart_all,
                                                               int* __restrict__ cursor_all,
                                                               float* __restrict__ dinv,
                                                               int N, int nblk, int E) {
    int t = threadIdx.x;
    int seg = (blockIdx.x >= nblk) ? 1 : 0;
    int lb  = blockIdx.x - seg * nblk;
    int i   = lb * SCAN_B + t;
    if (i < N) {
        int j  = seg * (N + 1) + i;
        int rs = rowstart_all[j] + bsum[blockIdx.x];
        rowstart_all[j] = rs;
        cursor_all[j]   = rs;
        if (seg == 0) dinv[i] = rsqrtf((float)deg[i] + 1.0f);
    }
    if (blockIdx.x == 0 && t == 0) {
        rowstart_all[N] = E;
        rowstart_all[(N + 1) + N] = E;
    }
}

// fill CSR colidx (gather list by dst) + CSC payload (c=dinv_s*dinv_d, g=batch[d])
__global__ void fill_kernel(const int* __restrict__ ei,
                            const float* __restrict__ dinv,
                            const int* __restrict__ batch,
                            int* __restrict__ cursor_all,
                            int* __restrict__ colidx,
                            float2* __restrict__ payload,
                            int E, int N) {
    int e = blockIdx.x * blockDim.x + threadIdx.x;
    if (e >= E) return;
    int s = ei[e], d = ei[E + e];
    if (s < 0) s = 0; if (s >= N) s = N - 1;
    if (d < 0) d = 0; if (d >= N) d = N - 1;
    // CSR (by dst): source list for the pull-gather
    int slot1 = atomicAdd(&cursor_all[d], 1);
    if (slot1 >= 0 && slot1 < E) colidx[slot1] = s;
    // CSC (by src): payload for the push-pool
    int g = batch[d];
    if (g < 0) g = 0; if (g >= NGRAPH) g = NGRAPH - 1;
    int slot2 = atomicAdd(&cursor_all[(N + 1) + s], 1);
    if (slot2 >= 0 && slot2 < E)
        payload[slot2] = make_float2(dinv[s] * dinv[d], __int_as_float(g));
}

// --- Layer-1 aggregation (pull): AGG_i = dinv_i*(sum_e dinv_s*x_s + dinv_i*x_i)
// Half-wave (32 lanes) per node, float4/lane (512B row in one request), unroll2.
__global__ __launch_bounds__(256) void agg1_kernel(const float* __restrict__ X,
                                                   const int* __restrict__ rowstart,
                                                   const int* __restrict__ colidx,
                                                   const float* __restrict__ dinv,
                                                   float* __restrict__ AGG,
                                                   int N, int chunk) {
    int hid  = blockIdx.x * 8 + (threadIdx.x >> 5);
    int lane = threadIdx.x & 31;
    int i0 = hid * chunk, i1 = min(i0 + chunk, N);
    for (int i = i0; i < i1; ++i) {
        float di = dinv[i];
        float4 xv = *(const float4*)(X + (size_t)i * D + lane * 4);
        float4 acc;
        acc.x = di * xv.x; acc.y = di * xv.y; acc.z = di * xv.z; acc.w = di * xv.w;
        int e0 = rowstart[i], e1 = rowstart[i + 1];
        int e = e0;
        if ((e1 - e0) & 1) {
            int s = colidx[e++];
            float ds = dinv[s];
            float4 v = *(const float4*)(X + (size_t)s * D + lane * 4);
            acc.x = fmaf(ds, v.x, acc.x); acc.y = fmaf(ds, v.y, acc.y);
            acc.z = fmaf(ds, v.z, acc.z); acc.w = fmaf(ds, v.w, acc.w);
        }
        for (; e < e1; e += 2) {
            int s0 = colidx[e], s1 = colidx[e + 1];
            float4 v0 = *(const float4*)(X + (size_t)s0 * D + lane * 4);
            float4 v1 = *(const float4*)(X + (size_t)s1 * D + lane * 4);
            float d0 = dinv[s0], d1 = dinv[s1];
            acc.x = fmaf(d0, v0.x, acc.x); acc.y = fmaf(d0, v0.y, acc.y);
            acc.z = fmaf(d0, v0.z, acc.z); acc.w = fmaf(d0, v0.w, acc.w);
            acc.x = fmaf(d1, v1.x, acc.x); acc.y = fmaf(d1, v1.y, acc.y);
            acc.z = fmaf(d1, v1.z, acc.z); acc.w = fmaf(d1, v1.w, acc.w);
        }
        float4 o;
        o.x = di * acc.x; o.y = di * acc.y; o.z = di * acc.z; o.w = di * acc.w;
        *(float4*)(AGG + (size_t)i * D + lane * 4) = o;
    }
}

// --- In-place GEMM: M = relu(M @ W1 + b1), fp32, LDS-staged A-tile ----------
__global__ __launch_bounds__(256) void gemm_relu_kernel(float* __restrict__ M,
                                                        const float* __restrict__ W,
                                                        const float* __restrict__ bias,
                                                        int N) {
    __shared__ float Alds[64][D];
    int t = threadIdx.x;
    int row0 = blockIdx.x * 64;
    {
        int c4 = (t & 31) * 4;
        int rsub = t >> 5;
#pragma unroll
        for (int rr = 0; rr < 8; ++rr) {
            int r = rr * 8 + rsub;
            int row = row0 + r;
            if (row >= N) row = N - 1;
            float4 v = *(const float4*)(M + (size_t)row * D + c4);
            *(float4*)&Alds[r][c4] = v;
        }
    }
    __syncthreads();

    int tx = t & 31, ty = t >> 5;
    float4 acc[8];
#pragma unroll
    for (int r = 0; r < 8; ++r) acc[r] = make_float4(0.f, 0.f, 0.f, 0.f);

    for (int k = 0; k < D; ++k) {
        float4 w = *(const float4*)(W + (size_t)k * D + tx * 4);
#pragma unroll
        for (int r = 0; r < 8; ++r) {
            float a = Alds[ty * 8 + r][k];
            acc[r].x = fmaf(a, w.x, acc[r].x);
            acc[r].y = fmaf(a, w.y, acc[r].y);
            acc[r].z = fmaf(a, w.z, acc[r].z);
            acc[r].w = fmaf(a, w.w, acc[r].w);
        }
    }

    float4 bv = *(const float4*)(bias + tx * 4);
#pragma unroll
    for (int r = 0; r < 8; ++r) {
        int row = row0 + ty * 8 + r;
        if (row < N) {
            float4 o;
            o.x = fmaxf(acc[r].x + bv.x, 0.f);
            o.y = fmaxf(acc[r].y + bv.y, 0.f);
            o.z = fmaxf(acc[r].z + bv.z, 0.f);
            o.w = fmaxf(acc[r].w + bv.w, 0.f);
            *(float4*)(M + (size_t)row * D + tx * 4) = o;
        }
    }
}

// --- Layer-2 + pool, PUSH form ----------------------------------------------
// Stream h rows once (coalesced); per out-edge scatter c*h into LDS pool
// replica; flush via global atomics. Self term dinv_s^2*h_s included.
__global__ __launch_bounds__(256) void agg2_pool_push(const float* __restrict__ H,
                                                      const int* __restrict__ rs_src,
                                                      const float2* __restrict__ payload,
                                                      const float* __restrict__ dinv,
                                                      const int* __restrict__ batch,
                                                      float* __restrict__ pool,
                                                      int N, int chunk) {
    __shared__ float lp[NGRAPH * D];  // 32 KB
    for (int j = threadIdx.x; j < NGRAPH * D; j += 256) lp[j] = 0.f;
    __syncthreads();

    int gid  = blockIdx.x * 4 + (threadIdx.x >> 6);
    int lane = threadIdx.x & 63;
    int i0 = gid * chunk, i1 = min(i0 + chunk, N);
    for (int s = i0; s < i1; ++s) {
        float2 h = ((const float2*)(H + (size_t)s * D))[lane];
        float ds = dinv[s];
        int gs = batch[s];
        if (gs < 0) gs = 0; if (gs >= NGRAPH) gs = NGRAPH - 1;
        float cs = ds * ds;
        atomicAdd(&lp[gs * D + 2 * lane],     cs * h.x);
        atomicAdd(&lp[gs * D + 2 * lane + 1], cs * h.y);
        int e0 = rs_src[s], e1 = rs_src[s + 1];
        for (int e = e0; e < e1; ++e) {
            float2 p = payload[e];             // wave-uniform 8B load
            float c = p.x;
            int   g = __float_as_int(p.y);
            atomicAdd(&lp[g * D + 2 * lane],     c * h.x);
            atomicAdd(&lp[g * D + 2 * lane + 1], c * h.y);
        }
    }
    __syncthreads();
    for (int j = threadIdx.x; j < NGRAPH * D; j += 256) {
        float v = lp[j];
        if (v != 0.f) atomicAdd(&pool[j], v);
    }
}

// --- Final tiny GEMM: out[g][o] = (pool[g]/cnt_g) . W2[:,o] + b2[o] ---------
__device__ __forceinline__ int lbound(const int* __restrict__ a, int n, int v) {
    int lo = 0, hi = n;
    while (lo < hi) {
        int m = (lo + hi) >> 1;
        if (a[m] < v) lo = m + 1; else hi = m;
    }
    return lo;
}

__global__ void final_gemm_kernel(const float* __restrict__ pool,
                                  const int* __restrict__ batch,
                                  const float* __restrict__ W2,
                                  const float* __restrict__ b2,
                                  float* __restrict__ out, int N) {
    int g = blockIdx.x, o = threadIdx.x;
    int s = lbound(batch, N, g);
    int e = lbound(batch, N, g + 1);
    float inv_cnt = 1.0f / fmaxf((float)(e - s), 1.0f);
    float acc = 0.f;
#pragma unroll 4
    for (int k = 0; k < D; ++k)
        acc = fmaf(pool[g * D + k], W2[k * D + o], acc);
    out[g * D + o] = acc * inv_cnt + b2[o];
}

// ---------------------------------------------------------------------------

extern "C" void kernel_launch(void* const* d_in, const int* in_sizes, int n_in,
                              void* d_out, int out_size, void* d_ws, size_t ws_size,
                              hipStream_t stream) {
    const float* x     = (const float*)d_in[0];
    const int*   ei    = (const int*)  d_in[1];
    const int*   batch = (const int*)  d_in[2];
    const float* W1    = (const float*)d_in[3];
    const float* b1    = (const float*)d_in[4];
    const float* W2    = (const float*)d_in[5];
    const float* b2    = (const float*)d_in[6];
    float* out = (float*)d_out;

    const int N = in_sizes[0] / D;
    const int E = in_sizes[1] / 2;
    const int nblk = (N + SCAN_B - 1) / SCAN_B;   // <=64 for N<=65536

    // workspace carve-up (256B aligned) — total ~37 MB
    char* ws = (char*)d_ws;
    size_t off = 0;
    auto carve = [&](size_t bytes) {
        size_t o = off;
        off = (off + bytes + 255) & ~(size_t)255;
        return o;
    };
    size_t o_deg      = carve((size_t)2 * N * 4);          // dst | src degrees
    size_t o_rowstart = carve((size_t)2 * (N + 1) * 4);    // dst | src rowstarts
    size_t o_cursor   = carve((size_t)2 * (N + 1) * 4);
    size_t o_dinv     = carve((size_t)N * 4);
    size_t o_colidx   = carve((size_t)E * 4);              // CSR: src by dst
    size_t o_payload  = carve((size_t)E * 8);              // CSC: (c,g) by src
    size_t o_bsum     = carve((size_t)128 * 4);
    size_t o_pool     = carve((size_t)NGRAPH * D * 4);
    size_t o_agg      = carve((size_t)N * D * 4);
    size_t need = off;

    if (ws_size < need) {
        zero_out_kernel<<<(out_size + 255) / 256, 256, 0, stream>>>(out, out_size);
        return;
    }

    int*    deg      = (int*)   (ws + o_deg);
    int*    rowstart = (int*)   (ws + o_rowstart);   // [0..N] dst, [N+1..2N+1] src
    int*    cursor   = (int*)   (ws + o_cursor);
    float*  dinv     = (float*) (ws + o_dinv);
    int*    colidx   = (int*)   (ws + o_colidx);
    float2* payload  = (float2*)(ws + o_payload);
    int*    bsum     = (int*)   (ws + o_bsum);
    float*  pool     = (float*) (ws + o_pool);
    float*  AGG      = (float*) (ws + o_agg);

    hipMemsetAsync(deg, 0, (size_t)2 * N * 4, stream);
    hipMemsetAsync(pool, 0, (size_t)NGRAPH * D * 4, stream);

    int eb = (E + 255) / 256;
    count_kernel<<<eb, 256, 0, stream>>>(ei, deg, E, N);
    block_scan_kernel<<<2 * nblk, SCAN_B, 0, stream>>>(deg, rowstart, bsum, N, nblk);
    scan_sums_kernel<<<1, 128, 0, stream>>>(bsum, nblk);
    finalize_scan_kernel<<<2 * nblk, SCAN_B, 0, stream>>>(deg, bsum, rowstart, cursor,
                                                          dinv, N, nblk, E);
    fill_kernel<<<eb, 256, 0, stream>>>(ei, dinv, batch, cursor, colidx, payload, E, N);

    // layer 1: AGG = A_hat X   (pull gather, half-wave/node)
    int halves = AGG_BLOCKS * 8;
    int chunk1 = (N + halves - 1) / halves;
    agg1_kernel<<<AGG_BLOCKS, 256, 0, stream>>>(x, rowstart, colidx, dinv, AGG, N, chunk1);
    // layer 1: AGG = relu(AGG @ W1 + b1)
    int gb = (N + 63) / 64;
    gemm_relu_kernel<<<gb, 256, 0, stream>>>(AGG, W1, b1, N);
    // layer 2 + pool numerator (push form over CSC)
    int pgroups = PUSH_BLOCKS * 4;
    int chunk2  = (N + pgroups - 1) / pgroups;
    agg2_pool_push<<<PUSH_BLOCKS, 256, 0, stream>>>(AGG, rowstart + (N + 1), payload,
                                                    dinv, batch, pool, N, chunk2);
    // out = (pool/cnt) @ W2 + b2
    final_gemm_kernel<<<NGRAPH, D, 0, stream>>>(pool, batch, W2, b2, out, N);
}

// Round 7
// 279.337 us; speedup vs baseline: 2.7554x; 2.7554x over previous
//
#include <hip/hip_runtime.h>

// ---------------------------------------------------------------------------
// 2-layer GCN + global mean pool, MI355X (gfx950).
//   A_hat = D^{-1/2}(A+I)D^{-1/2}
//   H   = relu( A_hat (X W1) + b1 )      [GEMM first, then pull-aggregate]
//   out = pool( A_hat H ) @ W2 + b2      [pool-first: no relu on layer 2]
// R7: revert R6's push (475us, latency-serialized) -> pull. New: gathered
// operands stored fp16 with dinv folded in (G' = dinv*(X@W1), H'' = dinv*H),
// halving gather bytes and killing per-edge dinv loads. CSC build dropped.
// ---------------------------------------------------------------------------

#define D 128
#define NGRAPH 64
#define AGG_BLOCKS 2048   // 8192 wave-groups
#define SCAN_B 1024

typedef _Float16 h16x2 __attribute__((ext_vector_type(2)));

__device__ __forceinline__ float2 h2f(unsigned u) {
    h16x2 h = __builtin_bit_cast(h16x2, u);
    return make_float2((float)h.x, (float)h.y);
}
__device__ __forceinline__ unsigned f2h(float x, float y) {
    h16x2 h;
    h.x = (_Float16)x;
    h.y = (_Float16)y;
    return __builtin_bit_cast(unsigned, h);
}

// --- diagnostic: all-zero output (ws too small) ----------------------------
__global__ void zero_out_kernel(float* __restrict__ out, int n) {
    int i = blockIdx.x * blockDim.x + threadIdx.x;
    if (i < n) out[i] = 0.f;
}

// --- CSR build (by dst) -----------------------------------------------------
__global__ void count_kernel(const int* __restrict__ ei, int* __restrict__ deg,
                             int E, int N) {
    int e = blockIdx.x * blockDim.x + threadIdx.x;
    if (e < E) {
        int d = ei[E + e];
        if (d >= 0 && d < N) atomicAdd(&deg[d], 1);
    }
}

__global__ __launch_bounds__(SCAN_B) void block_scan_kernel(const int* __restrict__ deg,
                                                            int* __restrict__ rowstart,
                                                            int* __restrict__ bsum,
                                                            int N) {
    __shared__ int sc[SCAN_B];
    int t = threadIdx.x;
    int i = blockIdx.x * SCAN_B + t;
    int v = (i < N) ? deg[i] : 0;
    int orig = v;
    sc[t] = v;
    __syncthreads();
    for (int off = 1; off < SCAN_B; off <<= 1) {
        int add = (t >= off) ? sc[t - off] : 0;
        __syncthreads();
        v += add;
        sc[t] = v;
        __syncthreads();
    }
    if (i < N) rowstart[i] = v - orig;           // local exclusive
    if (t == SCAN_B - 1) bsum[blockIdx.x] = v;
}

__global__ __launch_bounds__(64) void scan_sums_kernel(int* __restrict__ bsum,
                                                       int* __restrict__ rowstart,
                                                       int nblk, int N) {
    int lane = threadIdx.x;
    int v = (lane < nblk) ? bsum[lane] : 0;
    int orig = v;
    for (int off = 1; off < 64; off <<= 1) {
        int u = __shfl_up(v, off);
        if (lane >= off) v += u;
    }
    if (lane < nblk) bsum[lane] = v - orig;
    if (lane == nblk - 1) rowstart[N] = v;
}

__global__ __launch_bounds__(SCAN_B) void finalize_scan_kernel(const int* __restrict__ deg,
                                                               const int* __restrict__ bsum,
                                                               int* __restrict__ rowstart,
                                                               int* __restrict__ cursor,
                                                               float* __restrict__ dinv,
                                                               int N) {
    int i = blockIdx.x * SCAN_B + threadIdx.x;
    if (i < N) {
        int rs = rowstart[i] + bsum[blockIdx.x];
        rowstart[i] = rs;
        cursor[i]   = rs;
        dinv[i]     = rsqrtf((float)deg[i] + 1.0f);
    }
}

__global__ void fill_kernel(const int* __restrict__ ei, int* __restrict__ cursor,
                            int* __restrict__ colidx, int E, int N) {
    int e = blockIdx.x * blockDim.x + threadIdx.x;
    if (e < E) {
        int d = ei[E + e];
        if (d >= 0 && d < N) {
            int slot = atomicAdd(&cursor[d], 1);
            if (slot >= 0 && slot < E) {
                int s = ei[e];
                colidx[slot] = min(max(s, 0), N - 1);
            }
        }
    }
}

// --- GEMM: G' = dinv * (X @ W1), X fp32 [N,128] -> G' fp16 [N,128] ----------
// 256 thr/block, 64-row tile staged in LDS (32 KB); thread (tx,ty) owns
// rows ty*8..+7 x cols tx*4..+3.
__global__ __launch_bounds__(256) void gemm_kernel(const float* __restrict__ X,
                                                   const float* __restrict__ W,
                                                   const float* __restrict__ dinv,
                                                   unsigned* __restrict__ Gh,  // fp16x2 rows
                                                   int N) {
    __shared__ float Alds[64][D];
    int t = threadIdx.x;
    int row0 = blockIdx.x * 64;
    {
        int c4 = (t & 31) * 4;
        int rsub = t >> 5;
#pragma unroll
        for (int rr = 0; rr < 8; ++rr) {
            int r = rr * 8 + rsub;
            int row = row0 + r;
            if (row >= N) row = N - 1;
            float4 v = *(const float4*)(X + (size_t)row * D + c4);
            *(float4*)&Alds[r][c4] = v;
        }
    }
    __syncthreads();

    int tx = t & 31, ty = t >> 5;
    float4 acc[8];
#pragma unroll
    for (int r = 0; r < 8; ++r) acc[r] = make_float4(0.f, 0.f, 0.f, 0.f);

    for (int k = 0; k < D; ++k) {
        float4 w = *(const float4*)(W + (size_t)k * D + tx * 4);
#pragma unroll
        for (int r = 0; r < 8; ++r) {
            float a = Alds[ty * 8 + r][k];
            acc[r].x = fmaf(a, w.x, acc[r].x);
            acc[r].y = fmaf(a, w.y, acc[r].y);
            acc[r].z = fmaf(a, w.z, acc[r].z);
            acc[r].w = fmaf(a, w.w, acc[r].w);
        }
    }

#pragma unroll
    for (int r = 0; r < 8; ++r) {
        int row = row0 + ty * 8 + r;
        if (row < N) {
            float dv = dinv[row];
            uint2 o;
            o.x = f2h(dv * acc[r].x, dv * acc[r].y);
            o.y = f2h(dv * acc[r].z, dv * acc[r].w);
            // halves index row*D + tx*4 -> uint index row*64 + tx*2 (8B aligned)
            *(uint2*)(Gh + (size_t)row * (D / 2) + tx * 2) = o;
        }
    }
}

// --- agg1 (pull): H''_i = dinv_i * relu(dinv_i * (sum_e G'_s + G'_i) + b1) --
// Wave per node; 1 uint (fp16x2) per lane = one 256B request per edge.
__global__ __launch_bounds__(256) void agg1_kernel(const unsigned* __restrict__ Gh,
                                                   const int* __restrict__ rowstart,
                                                   const int* __restrict__ colidx,
                                                   const float* __restrict__ dinv,
                                                   const float* __restrict__ b1,
                                                   unsigned* __restrict__ Hh,
                                                   int N, int chunk) {
    int gid  = blockIdx.x * 4 + (threadIdx.x >> 6);
    int lane = threadIdx.x & 63;
    int i0 = gid * chunk, i1 = min(i0 + chunk, N);
    float bx = b1[2 * lane], by = b1[2 * lane + 1];
    for (int i = i0; i < i1; ++i) {
        float di = dinv[i];
        float2 acc = h2f(Gh[(size_t)i * (D / 2) + lane]);  // self term G'_i
        int e0 = rowstart[i], e1 = rowstart[i + 1];
        int e = e0;
        if ((e1 - e0) & 1) {
            int s = colidx[e++];
            float2 v = h2f(Gh[(size_t)s * (D / 2) + lane]);
            acc.x += v.x;
            acc.y += v.y;
        }
        for (; e < e1; e += 2) {
            int s0 = colidx[e], s1 = colidx[e + 1];
            float2 v0 = h2f(Gh[(size_t)s0 * (D / 2) + lane]);
            float2 v1 = h2f(Gh[(size_t)s1 * (D / 2) + lane]);
            acc.x += v0.x + v1.x;
            acc.y += v0.y + v1.y;
        }
        float hx = fmaxf(fmaf(di, acc.x, bx), 0.f) * di;   // H'' = dinv*relu(..)
        float hy = fmaxf(fmaf(di, acc.y, by), 0.f) * di;
        Hh[(size_t)i * (D / 2) + lane] = f2h(hx, hy);
    }
}

// --- agg2 (pull) + pool: pool[batch_i] += dinv_i*(sum_e H''_s + H''_i) ------
// batch sorted: accumulate locally, flush on graph change.
__global__ __launch_bounds__(256) void agg2_pool_kernel(const unsigned* __restrict__ Hh,
                                                        const int* __restrict__ rowstart,
                                                        const int* __restrict__ colidx,
                                                        const float* __restrict__ dinv,
                                                        const int* __restrict__ batch,
                                                        float* __restrict__ pool,
                                                        int N, int chunk) {
    int gid  = blockIdx.x * 4 + (threadIdx.x >> 6);
    int lane = threadIdx.x & 63;
    int i0 = gid * chunk, i1 = min(i0 + chunk, N);
    if (i0 >= N) return;

    float2 acc = make_float2(0.f, 0.f);
    int cur = min(max(batch[i0], 0), NGRAPH - 1);
    for (int i = i0; i < i1; ++i) {
        float di = dinv[i];
        float2 a = h2f(Hh[(size_t)i * (D / 2) + lane]);    // self term H''_i
        int e0 = rowstart[i], e1 = rowstart[i + 1];
        int e = e0;
        if ((e1 - e0) & 1) {
            int s = colidx[e++];
            float2 v = h2f(Hh[(size_t)s * (D / 2) + lane]);
            a.x += v.x;
            a.y += v.y;
        }
        for (; e < e1; e += 2) {
            int s0 = colidx[e], s1 = colidx[e + 1];
            float2 v0 = h2f(Hh[(size_t)s0 * (D / 2) + lane]);
            float2 v1 = h2f(Hh[(size_t)s1 * (D / 2) + lane]);
            a.x += v0.x + v1.x;
            a.y += v0.y + v1.y;
        }
        int b = min(max(batch[i], 0), NGRAPH - 1);
        if (b != cur) {
            atomicAdd(&pool[(size_t)cur * D + 2 * lane], acc.x);
            atomicAdd(&pool[(size_t)cur * D + 2 * lane + 1], acc.y);
            acc = make_float2(0.f, 0.f);
            cur = b;
        }
        acc.x = fmaf(di, a.x, acc.x);
        acc.y = fmaf(di, a.y, acc.y);
    }
    atomicAdd(&pool[(size_t)cur * D + 2 * lane], acc.x);
    atomicAdd(&pool[(size_t)cur * D + 2 * lane + 1], acc.y);
}

// --- Final tiny GEMM: out[g][o] = (pool[g]/cnt_g) . W2[:,o] + b2[o] ---------
__device__ __forceinline__ int lbound(const int* __restrict__ a, int n, int v) {
    int lo = 0, hi = n;
    while (lo < hi) {
        int m = (lo + hi) >> 1;
        if (a[m] < v) lo = m + 1; else hi = m;
    }
    return lo;
}

__global__ void final_gemm_kernel(const float* __restrict__ pool,
                                  const int* __restrict__ batch,
                                  const float* __restrict__ W2,
                                  const float* __restrict__ b2,
                                  float* __restrict__ out, int N) {
    int g = blockIdx.x, o = threadIdx.x;
    int s = lbound(batch, N, g);
    int e = lbound(batch, N, g + 1);
    float inv_cnt = 1.0f / fmaxf((float)(e - s), 1.0f);
    float acc = 0.f;
#pragma unroll 4
    for (int k = 0; k < D; ++k)
        acc = fmaf(pool[g * D + k], W2[k * D + o], acc);
    out[g * D + o] = acc * inv_cnt + b2[o];
}

// ---------------------------------------------------------------------------

extern "C" void kernel_launch(void* const* d_in, const int* in_sizes, int n_in,
                              void* d_out, int out_size, void* d_ws, size_t ws_size,
                              hipStream_t stream) {
    const float* x     = (const float*)d_in[0];
    const int*   ei    = (const int*)  d_in[1];
    const int*   batch = (const int*)  d_in[2];
    const float* W1    = (const float*)d_in[3];
    const float* b1    = (const float*)d_in[4];
    const float* W2    = (const float*)d_in[5];
    const float* b2    = (const float*)d_in[6];
    float* out = (float*)d_out;

    const int N = in_sizes[0] / D;
    const int E = in_sizes[1] / 2;
    const int nblk = (N + SCAN_B - 1) / SCAN_B;   // <=64 for N<=65536

    // workspace carve-up (256B aligned) — total ~29 MB
    char* ws = (char*)d_ws;
    size_t off = 0;
    auto carve = [&](size_t bytes) {
        size_t o = off;
        off = (off + bytes + 255) & ~(size_t)255;
        return o;
    };
    size_t o_deg      = carve((size_t)N * 4);
    size_t o_rowstart = carve((size_t)(N + 1) * 4);
    size_t o_cursor   = carve((size_t)(N + 1) * 4);
    size_t o_dinv     = carve((size_t)N * 4);
    size_t o_colidx   = carve((size_t)E * 4);
    size_t o_bsum     = carve((size_t)64 * 4);
    size_t o_pool     = carve((size_t)NGRAPH * D * 4);
    size_t o_gh       = carve((size_t)N * D * 2);   // fp16 G'
    size_t o_hh       = carve((size_t)N * D * 2);   // fp16 H''
    size_t need = off;

    if (ws_size < need) {
        zero_out_kernel<<<(out_size + 255) / 256, 256, 0, stream>>>(out, out_size);
        return;
    }

    int*      deg      = (int*)     (ws + o_deg);
    int*      rowstart = (int*)     (ws + o_rowstart);
    int*      cursor   = (int*)     (ws + o_cursor);
    float*    dinv     = (float*)   (ws + o_dinv);
    int*      colidx   = (int*)     (ws + o_colidx);
    int*      bsum     = (int*)     (ws + o_bsum);
    float*    pool     = (float*)   (ws + o_pool);
    unsigned* Gh       = (unsigned*)(ws + o_gh);
    unsigned* Hh       = (unsigned*)(ws + o_hh);

    hipMemsetAsync(deg, 0, (size_t)N * 4, stream);
    hipMemsetAsync(pool, 0, (size_t)NGRAPH * D * 4, stream);

    int eb = (E + 255) / 256;
    count_kernel<<<eb, 256, 0, stream>>>(ei, deg, E, N);
    block_scan_kernel<<<nblk, SCAN_B, 0, stream>>>(deg, rowstart, bsum, N);
    scan_sums_kernel<<<1, 64, 0, stream>>>(bsum, rowstart, nblk, N);
    finalize_scan_kernel<<<nblk, SCAN_B, 0, stream>>>(deg, bsum, rowstart, cursor, dinv, N);
    fill_kernel<<<eb, 256, 0, stream>>>(ei, cursor, colidx, E, N);

    // G' = dinv * (X @ W1), fp16
    int gb = (N + 63) / 64;
    gemm_kernel<<<gb, 256, 0, stream>>>(x, W1, dinv, Gh, N);

    int groups = AGG_BLOCKS * 4;
    int chunk  = (N + groups - 1) / groups;
    // H'' = dinv * relu(dinv * (A-sum of G') + b1), fp16
    agg1_kernel<<<AGG_BLOCKS, 256, 0, stream>>>(Gh, rowstart, colidx, dinv, b1, Hh, N, chunk);
    // pool numerator from H''
    agg2_pool_kernel<<<AGG_BLOCKS, 256, 0, stream>>>(Hh, rowstart, colidx, dinv,
                                                     batch, pool, N, chunk);
    // out = (pool/cnt) @ W2 + b2
    final_gemm_kernel<<<NGRAPH, D, 0, stream>>>(pool, batch, W2, b2, out, N);
}